// Round 5
// baseline (263.481 us; speedup 1.0000x reference)
//
#include <hip/hip_runtime.h>
#include <hip/hip_bf16.h>

#define BS   8192
#define DIM  768
#define TM   256
#define TN   256
#define BK   128
#define NIT  (DIM / BK)     // 6
#define GRID ((BS / TM) * (BS / TN))   // 1024

typedef float f32x4 __attribute__((ext_vector_type(4)));
typedef int   i32x4 __attribute__((ext_vector_type(4)));
typedef int   i32x8 __attribute__((ext_vector_type(8)));

__device__ __forceinline__ void async16(const void* g, void* l) {
    __builtin_amdgcn_global_load_lds(
        (const __attribute__((address_space(1))) unsigned int*)g,
        (__attribute__((address_space(3))) unsigned int*)l,
        16, 0, 0);
}

// One wave per row: L2-norm both embeddings, emit fp8 e4m3, diag sim in fp32.
// Blocks 0..63 also zero rowsum/colsum; block 0 zeroes the done-counter.
__global__ __launch_bounds__(256) void normalize_kernel(
    const float* __restrict__ text, const float* __restrict__ ctr,
    unsigned char* __restrict__ tq, unsigned char* __restrict__ cq,
    float* __restrict__ sim, float* __restrict__ rowsum, float* __restrict__ colsum,
    unsigned int* __restrict__ cnt) {
    if (blockIdx.x < 64) {
        const int i = blockIdx.x * 256 + threadIdx.x;   // covers 16384 = 2*BS
        rowsum[i] = 0.f;
        colsum[i] = 0.f;
    }
    if (blockIdx.x == 64 && threadIdx.x == 0) *cnt = 0u;
    const int lane = threadIdx.x & 63;
    const int row  = blockIdx.x * 4 + (threadIdx.x >> 6);
    const size_t base = (size_t)row * DIM;

    float4 t[3], c[3];
    float st = 0.f, sc = 0.f, sd = 0.f;
#pragma unroll
    for (int i = 0; i < 3; ++i) {
        t[i] = *(const float4*)&text[base + lane * 4 + i * 256];
        c[i] = *(const float4*)&ctr [base + lane * 4 + i * 256];
        st += t[i].x*t[i].x + t[i].y*t[i].y + t[i].z*t[i].z + t[i].w*t[i].w;
        sc += c[i].x*c[i].x + c[i].y*c[i].y + c[i].z*c[i].z + c[i].w*c[i].w;
        sd += t[i].x*c[i].x + t[i].y*c[i].y + t[i].z*c[i].z + t[i].w*c[i].w;
    }
#pragma unroll
    for (int off = 1; off < 64; off <<= 1) {
        st += __shfl_xor(st, off);
        sc += __shfl_xor(sc, off);
        sd += __shfl_xor(sd, off);
    }
    const float invt = 1.0f / fmaxf(sqrtf(st), 1e-8f);
    const float invc = 1.0f / fmaxf(sqrtf(sc), 1e-8f);
#pragma unroll
    for (int i = 0; i < 3; ++i) {
        unsigned int wt = (unsigned int)__builtin_amdgcn_cvt_pk_fp8_f32(t[i].x * invt, t[i].y * invt, 0, false);
        wt = (unsigned int)__builtin_amdgcn_cvt_pk_fp8_f32(t[i].z * invt, t[i].w * invt, (int)wt, true);
        unsigned int wcq = (unsigned int)__builtin_amdgcn_cvt_pk_fp8_f32(c[i].x * invc, c[i].y * invc, 0, false);
        wcq = (unsigned int)__builtin_amdgcn_cvt_pk_fp8_f32(c[i].z * invc, c[i].w * invc, (int)wcq, true);
        *(unsigned int*)&tq[base + lane * 4 + i * 256] = wt;
        *(unsigned int*)&cq[base + lane * 4 + i * 256] = wcq;
    }
    if (lane == 0) sim[row] = sd * invt * invc;
}

// MX-scaled fp8 GEMM, 256x256 macro-tile, BK=128, 1024 threads / 16 waves (4x4),
// double-buffered LDS (2 x 64 KB), ONE barrier per K-iter: prefetch for iter
// k+1 issues right after the barrier, giving loads ~2x the time they need
// (compute 2200 cy vs staging 1024 cy per CU per iter) so the vmcnt(0) drain
// at the next barrier is ~free. Fragment layout + half-swizzle identical to
// the R3/R4-verified scheme (SQ_LDS_BANK_CONFLICT == 0).
// Last block (agent-scope done-counter) computes the final loss.
__global__ __launch_bounds__(1024) void gemm_lse_kernel(
    const unsigned char* __restrict__ tq, const unsigned char* __restrict__ cq,
    float* __restrict__ rowsum, float* __restrict__ colsum,
    const float* __restrict__ sim, unsigned int* __restrict__ cnt,
    float* __restrict__ out) {
    __shared__ char lds[2 * 65536];   // [buf][A 32K | B 32K] = 128 KB

    const int tid = threadIdx.x;

    // XCD-banded swizzle: XCD x owns tile-rows [4x, 4x+4), sweeping columns.
    const int bid = blockIdx.x;
    const int xcd = bid & 7, idx = bid >> 3;
    const int rowBase = (xcd * 4 + (idx & 3)) * TM;
    const int colBase = (idx >> 2) * TN;

    const int wave = tid >> 6, lane = tid & 63;
    const int wr = wave >> 2, wc = wave & 3;        // 4x4 wave grid: 64x64 each
    const int quad = lane >> 4, l16 = lane & 15;

    // Staging: per buffer, A = 2048 16B chunks ([kc(4)][row(256)][half-swizz 32B]),
    // B same. Thread owns chunks tid, tid+1024 of each. LDS dest linear in tid.
    int gofs[2], lofs[2];
#pragma unroll
    for (int i = 0; i < 2; ++i) {
        const int p   = tid + i * 1024;
        const int kc  = p >> 9;
        const int row = (p >> 1) & 255;
        const int hl  = (p & 1) ^ (kc & 1);
        gofs[i] = row * DIM + kc * 32 + hl * 16;
        lofs[i] = p * 16;
    }
    const unsigned char* gA = tq + (size_t)rowBase * DIM;
    const unsigned char* gB = cq + (size_t)colBase * DIM;

    // Fragment addressing: lane (quad,l16) reads k-block kc=quad of its row;
    // physical half = logical half ^ (quad&1). kc plane = 256*32 = 8192 B.
    const int sw = quad & 1;
    int aoff[4], boff[4];
#pragma unroll
    for (int mt = 0; mt < 4; ++mt) aoff[mt] = quad * 8192 + (wr * 64 + mt * 16 + l16) * 32;
#pragma unroll
    for (int nt = 0; nt < 4; ++nt) boff[nt] = quad * 8192 + (wc * 64 + nt * 16 + l16) * 32;

    f32x4 acc[4][4];
#pragma unroll
    for (int mt = 0; mt < 4; ++mt)
#pragma unroll
        for (int nt = 0; nt < 4; ++nt)
            acc[mt][nt] = (f32x4){0.f, 0.f, 0.f, 0.f};

    // Prologue: stage K-chunk 0 into buffer 0.
#pragma unroll
    for (int i = 0; i < 2; ++i) {
        async16(gA + gofs[i], lds + lofs[i]);
        async16(gB + gofs[i], lds + 32768 + lofs[i]);
    }

    for (int it = 0; it < NIT; ++it) {
        __syncthreads();   // buf[it&1] ready; buf[(it+1)&1] free for writes
        if (it + 1 < NIT) {
            const int k0 = (it + 1) * BK;
            char* nb = lds + ((it + 1) & 1) * 65536;
#pragma unroll
            for (int i = 0; i < 2; ++i) {
                async16(gA + gofs[i] + k0, nb + lofs[i]);
                async16(gB + gofs[i] + k0, nb + 32768 + lofs[i]);
            }
        }
        const char* bA = lds + (it & 1) * 65536;
        const char* bB = bA + 32768;

        i32x8 bfr[4];
#pragma unroll
        for (int nt = 0; nt < 4; ++nt) {
            i32x4 lo = *(const i32x4*)(bB + boff[nt] + sw * 16);
            i32x4 hi = *(const i32x4*)(bB + boff[nt] + (sw ^ 1) * 16);
            bfr[nt] = __builtin_shufflevector(lo, hi, 0, 1, 2, 3, 4, 5, 6, 7);
        }
#pragma unroll
        for (int mt = 0; mt < 4; ++mt) {
            i32x4 lo = *(const i32x4*)(bA + aoff[mt] + sw * 16);
            i32x4 hi = *(const i32x4*)(bA + aoff[mt] + (sw ^ 1) * 16);
            i32x8 af = __builtin_shufflevector(lo, hi, 0, 1, 2, 3, 4, 5, 6, 7);
#pragma unroll
            for (int nt = 0; nt < 4; ++nt)
                acc[mt][nt] = __builtin_amdgcn_mfma_scale_f32_16x16x128_f8f6f4(
                    af, bfr[nt], acc[mt][nt], 0, 0, 0, 127, 0, 127);
        }
    }

    // Epilogue. D layout: col = l16 (ctr idx), row = quad*4 + reg (text idx).
    float rp[4][4];   // [mt][reg] partials over this wave's 64 cols
    float cp[4];      // [nt] partials over this wave's 64 rows
#pragma unroll
    for (int mt = 0; mt < 4; ++mt)
#pragma unroll
        for (int r = 0; r < 4; ++r) rp[mt][r] = 0.f;
#pragma unroll
    for (int nt = 0; nt < 4; ++nt) cp[nt] = 0.f;

#pragma unroll
    for (int mt = 0; mt < 4; ++mt)
#pragma unroll
        for (int nt = 0; nt < 4; ++nt)
#pragma unroll
            for (int r = 0; r < 4; ++r) {
                const float e = __expf(acc[mt][nt][r]);   // S in [-1,1]: no max needed
                rp[mt][r] += e;
                cp[nt]    += e;
            }

#pragma unroll
    for (int mt = 0; mt < 4; ++mt)
#pragma unroll
        for (int r = 0; r < 4; ++r) {
            float v = rp[mt][r];
            v += __shfl_xor(v, 1);
            v += __shfl_xor(v, 2);
            v += __shfl_xor(v, 4);
            v += __shfl_xor(v, 8);
            rp[mt][r] = v;
        }
    if (l16 == 0) {
#pragma unroll
        for (int mt = 0; mt < 4; ++mt)
#pragma unroll
            for (int r = 0; r < 4; ++r)
                atomicAdd(&rowsum[rowBase + wr * 64 + mt * 16 + quad * 4 + r], rp[mt][r]);
    }
#pragma unroll
    for (int nt = 0; nt < 4; ++nt) {
        float v = cp[nt];
        v += __shfl_xor(v, 16);
        v += __shfl_xor(v, 32);
        if (quad == 0)
            atomicAdd(&colsum[colBase + wc * 64 + nt * 16 + l16], v);
    }

    // ---- Fused finalize: last block to finish reduces the 16K sums. ----
    // __syncthreads drains vmcnt (all this block's atomics performed at the
    // coherence point) before tid 0 releases via the agent-scope counter.
    float* redf = (float*)lds;
    unsigned int* flagp = (unsigned int*)(lds + 128);
    __syncthreads();
    if (tid == 0) {
        unsigned int old = __hip_atomic_fetch_add(cnt, 1u, __ATOMIC_ACQ_REL,
                                                  __HIP_MEMORY_SCOPE_AGENT);
        *flagp = (old == GRID - 1) ? 1u : 0u;
    }
    __syncthreads();
    if (*flagp) {
        float a = 0.f;
        for (int j = tid; j < BS; j += 1024) {
            const float rs = __hip_atomic_load(&rowsum[j], __ATOMIC_RELAXED,
                                               __HIP_MEMORY_SCOPE_AGENT);
            const float cs = __hip_atomic_load(&colsum[j], __ATOMIC_RELAXED,
                                               __HIP_MEMORY_SCOPE_AGENT);
            a += __logf(rs) + __logf(cs) - 2.f * sim[j];
        }
#pragma unroll
        for (int off = 1; off < 64; off <<= 1) a += __shfl_xor(a, off);
        if (lane == 0) redf[wave] = a;
        __syncthreads();
        if (tid == 0) {
            float s = 0.f;
#pragma unroll
            for (int w = 0; w < 16; ++w) s += redf[w];
            out[0] = s / (float)BS;
        }
    }
}

extern "C" void kernel_launch(void* const* d_in, const int* in_sizes, int n_in,
                              void* d_out, int out_size, void* d_ws, size_t ws_size,
                              hipStream_t stream) {
    const float* text = (const float*)d_in[0];
    const float* ctr  = (const float*)d_in[1];

    char* ws = (char*)d_ws;
    const size_t embBytes = (size_t)BS * DIM;   // fp8: 6,291,456 bytes each
    unsigned char* tq = (unsigned char*)ws;
    unsigned char* cq = (unsigned char*)(ws + embBytes);
    float* sim    = (float*)(ws + 2 * embBytes);
    float* rowsum = (float*)(ws + 2 * embBytes + BS * sizeof(float));
    float* colsum = (float*)(ws + 2 * embBytes + 2 * BS * sizeof(float));
    unsigned int* cnt = (unsigned int*)(ws + 2 * embBytes + 3 * BS * sizeof(float));

    normalize_kernel<<<BS / 4, 256, 0, stream>>>(text, ctr, tq, cq, sim,
                                                 rowsum, colsum, cnt);

    gemm_lse_kernel<<<GRID, 1024, 0, stream>>>(tq, cq, rowsum, colsum, sim,
                                               cnt, (float*)d_out);
}